// Round 1
// baseline (6133.110 us; speedup 1.0000x reference)
//
#include <hip/hip_runtime.h>
#include <cstdint>
#include <cstddef>

#define NN   50000
#define NE   400000
#define FDIM 256
#define HDIM 512
#define CDIM 3
#define NBLK 6

typedef __attribute__((ext_vector_type(4))) float f4;

// ---------------- setup kernels ----------------

__global__ __launch_bounds__(256) void k_zero_i32(int* p, int n) {
  int i = blockIdx.x * 256 + threadIdx.x;
  if (i < n) p[i] = 0;
}

__global__ __launch_bounds__(256) void k_hist(const int* __restrict__ dst, int* __restrict__ cnt) {
  int e = blockIdx.x * 256 + threadIdx.x;
  if (e < NE) {
    int d = dst[e];
    if ((unsigned)d < (unsigned)NN) atomicAdd(&cnt[d], 1);
  }
}

__global__ __launch_bounds__(256) void k_dinv(const int* __restrict__ cnt, float* __restrict__ dinv) {
  int i = blockIdx.x * 256 + threadIdx.x;
  if (i < NN) dinv[i] = rsqrtf((float)cnt[i] + 1.0f);
}

// single-block exclusive scan of cnt[NN] -> row_start[NN+1]
__global__ __launch_bounds__(1024) void k_scan(const int* __restrict__ cnt, int* __restrict__ row_start) {
  __shared__ int wsum[16];
  __shared__ int carry_s;
  int tid = threadIdx.x, lane = tid & 63, wid = tid >> 6;
  if (tid == 0) carry_s = 0;
  __syncthreads();
  for (int base = 0; base < NN; base += 1024) {
    int i = base + tid;
    int v = (i < NN) ? cnt[i] : 0;
    int incl = v;
#pragma unroll
    for (int off = 1; off < 64; off <<= 1) {
      int t = __shfl_up(incl, off);
      if (lane >= off) incl += t;
    }
    if (lane == 63) wsum[wid] = incl;
    __syncthreads();
    int woff = 0;
    for (int w = 0; w < wid; ++w) woff += wsum[w];
    int excl = carry_s + woff + (incl - v);
    if (i < NN) row_start[i] = excl;
    __syncthreads();
    if (tid == 1023) carry_s = excl + v;
    __syncthreads();
  }
  if (threadIdx.x == 0) row_start[NN] = carry_s;
}

__global__ __launch_bounds__(256) void k_fill(const int* __restrict__ src, const int* __restrict__ dst,
    const int* __restrict__ row_start, int* __restrict__ fill,
    const float* __restrict__ dinv, int* __restrict__ csr_src, float* __restrict__ csr_coef) {
  int e = blockIdx.x * 256 + threadIdx.x;
  if (e >= NE) return;
  int s = src[e], d = dst[e];
  if ((unsigned)s >= (unsigned)NN || (unsigned)d >= (unsigned)NN) return;
  int pos = row_start[d] + atomicAdd(&fill[d], 1);
  csr_src[pos] = s;
  csr_coef[pos] = dinv[s] * dinv[d];
}

// ---------------- fp32 GEMM: C[M,512] = (relu?)A[M,K] @ B[K,512] ----------------

#define BM 128
#define BN 128
#define BK 16

__global__ __launch_bounds__(256) void k_gemm(const float* __restrict__ A, const float* __restrict__ B,
    float* __restrict__ C, int M, int K, int relu) {
  __shared__ float As[BK][BM];   // transposed: As[k][m]
  __shared__ float Bs[BK][BN];
  const int tid = threadIdx.x;
  const int tx = tid & 15, ty = tid >> 4;
  const int row0 = blockIdx.x * BM, col0 = blockIdx.y * BN;

  float acc[8][8];
#pragma unroll
  for (int i = 0; i < 8; ++i)
#pragma unroll
    for (int j = 0; j < 8; ++j) acc[i][j] = 0.f;

  for (int k0 = 0; k0 < K; k0 += BK) {
    // A tile: 128 rows x 16 cols = 512 float4s, 2 per thread
#pragma unroll
    for (int t = 0; t < 2; ++t) {
      int q = tid + t * 256;
      int ar = q >> 2, ac = (q & 3) * 4;
      int row = row0 + ar;
      f4 v = {0.f, 0.f, 0.f, 0.f};
      if (row < M) v = *(const f4*)(A + (size_t)row * K + k0 + ac);
      if (relu) {
        v.x = fmaxf(v.x, 0.f); v.y = fmaxf(v.y, 0.f);
        v.z = fmaxf(v.z, 0.f); v.w = fmaxf(v.w, 0.f);
      }
      As[ac + 0][ar] = v.x; As[ac + 1][ar] = v.y;
      As[ac + 2][ar] = v.z; As[ac + 3][ar] = v.w;
    }
    // B tile: 16 rows x 128 cols = 512 float4s, 2 per thread
#pragma unroll
    for (int t = 0; t < 2; ++t) {
      int q = tid + t * 256;
      int br_ = q >> 5, bc = (q & 31) * 4;
      f4 v = *(const f4*)(B + (size_t)(k0 + br_) * HDIM + col0 + bc);
      *(f4*)&Bs[br_][bc] = v;
    }
    __syncthreads();
#pragma unroll
    for (int kk = 0; kk < BK; ++kk) {
      f4 a0 = *(const f4*)&As[kk][ty * 8];
      f4 a1 = *(const f4*)&As[kk][ty * 8 + 4];
      f4 b0 = *(const f4*)&Bs[kk][tx * 8];
      f4 b1 = *(const f4*)&Bs[kk][tx * 8 + 4];
      float a[8] = {a0.x, a0.y, a0.z, a0.w, a1.x, a1.y, a1.z, a1.w};
      float b[8] = {b0.x, b0.y, b0.z, b0.w, b1.x, b1.y, b1.z, b1.w};
#pragma unroll
      for (int i = 0; i < 8; ++i)
#pragma unroll
        for (int j = 0; j < 8; ++j) acc[i][j] = fmaf(a[i], b[j], acc[i][j]);
    }
    __syncthreads();
  }
#pragma unroll
  for (int i = 0; i < 8; ++i) {
    int row = row0 + ty * 8 + i;
    if (row < M) {
      f4 o0 = {acc[i][0], acc[i][1], acc[i][2], acc[i][3]};
      f4 o1 = {acc[i][4], acc[i][5], acc[i][6], acc[i][7]};
      *(f4*)(C + (size_t)row * HDIM + col0 + tx * 8)     = o0;
      *(f4*)(C + (size_t)row * HDIM + col0 + tx * 8 + 4) = o1;
    }
  }
}

// ---------------- CSR aggregation: xout[i] = b + dinv[i]^2*h[i] + sum coef*h[src] ----------------
// one wave per node; lane covers 8 features (2 coalesced f4 chunks)

__global__ __launch_bounds__(256) void k_agg(const float* __restrict__ h, float* __restrict__ xout,
    const int* __restrict__ row_start, const int* __restrict__ csr_src,
    const float* __restrict__ csr_coef, const float* __restrict__ dinv,
    const float* __restrict__ bias) {
  int wid = threadIdx.x >> 6, lane = threadIdx.x & 63;
  int i = blockIdx.x * 4 + wid;
  if (i >= NN) return;
  int c0 = lane * 4, c1 = 256 + lane * 4;
  float di = dinv[i];
  float d2 = di * di;
  const float* hi = h + (size_t)i * HDIM;
  f4 acc0 = *(const f4*)(hi + c0) * d2;
  f4 acc1 = *(const f4*)(hi + c1) * d2;
  int e0 = row_start[i], e1 = row_start[i + 1];
  for (int e = e0; e < e1; ++e) {
    int s = csr_src[e];
    float c = csr_coef[e];
    const float* hs = h + (size_t)s * HDIM;
    acc0 += *(const f4*)(hs + c0) * c;
    acc1 += *(const f4*)(hs + c1) * c;
  }
  acc0 += *(const f4*)(bias + c0);
  acc1 += *(const f4*)(bias + c1);
  *(f4*)(xout + (size_t)i * HDIM + c0) = acc0;
  *(f4*)(xout + (size_t)i * HDIM + c1) = acc1;
}

__global__ __launch_bounds__(256) void k_relu4(float* x, int n4) {
  int i = blockIdx.x * 256 + threadIdx.x;
  if (i < n4) {
    f4* p = (f4*)x;
    f4 v = p[i];
    v.x = fmaxf(v.x, 0.f); v.y = fmaxf(v.y, 0.f);
    v.z = fmaxf(v.z, 0.f); v.w = fmaxf(v.w, 0.f);
    p[i] = v;
  }
}

// final conv: h3[N,3] = X[N,512] @ W1[512,3]; one wave per node
__global__ __launch_bounds__(256) void k_gemm3(const float* __restrict__ X, const float* __restrict__ W1,
    float* __restrict__ h3) {
  int wid = threadIdx.x >> 6, lane = threadIdx.x & 63;
  int i = blockIdx.x * 4 + wid;
  if (i >= NN) return;
  const float* xi = X + (size_t)i * HDIM;
  float a0 = 0.f, a1 = 0.f, a2 = 0.f;
#pragma unroll
  for (int t = 0; t < HDIM / 64; ++t) {
    int k = t * 64 + lane;
    float v = xi[k];
    a0 = fmaf(v, W1[k * 3 + 0], a0);
    a1 = fmaf(v, W1[k * 3 + 1], a1);
    a2 = fmaf(v, W1[k * 3 + 2], a2);
  }
#pragma unroll
  for (int off = 32; off > 0; off >>= 1) {
    a0 += __shfl_down(a0, off);
    a1 += __shfl_down(a1, off);
    a2 += __shfl_down(a2, off);
  }
  if (lane == 0) {
    h3[(size_t)i * 3 + 0] = a0;
    h3[(size_t)i * 3 + 1] = a1;
    h3[(size_t)i * 3 + 2] = a2;
  }
}

__global__ __launch_bounds__(256) void k_agg3(const float* __restrict__ h3, float* __restrict__ out,
    const int* __restrict__ row_start, const int* __restrict__ csr_src,
    const float* __restrict__ csr_coef, const float* __restrict__ dinv,
    const float* __restrict__ b1) {
  int i = blockIdx.x * 256 + threadIdx.x;
  if (i >= NN) return;
  float d2 = dinv[i] * dinv[i];
  float o0 = h3[(size_t)i * 3 + 0] * d2;
  float o1 = h3[(size_t)i * 3 + 1] * d2;
  float o2 = h3[(size_t)i * 3 + 2] * d2;
  int e0 = row_start[i], e1 = row_start[i + 1];
  for (int e = e0; e < e1; ++e) {
    int s = csr_src[e];
    float c = csr_coef[e];
    o0 = fmaf(c, h3[(size_t)s * 3 + 0], o0);
    o1 = fmaf(c, h3[(size_t)s * 3 + 1], o1);
    o2 = fmaf(c, h3[(size_t)s * 3 + 2], o2);
  }
  out[(size_t)i * 3 + 0] = o0 + b1[0];
  out[(size_t)i * 3 + 1] = o1 + b1[1];
  out[(size_t)i * 3 + 2] = o2 + b1[2];
}

// ---------------- launch ----------------

extern "C" void kernel_launch(void* const* d_in, const int* in_sizes, int n_in,
                              void* d_out, int out_size, void* d_ws, size_t ws_size,
                              hipStream_t stream) {
  const float* x  = (const float*)d_in[0];
  const int*   ei = (const int*)d_in[1];
  const float* W0 = (const float*)d_in[2];
  const float* b0 = (const float*)d_in[3];
  const float* Wr = (const float*)d_in[4];
  const float* br = (const float*)d_in[5];
  const float* W1 = (const float*)d_in[6];
  const float* b1 = (const float*)d_in[7];
  float* out = (float*)d_out;
  float* X = out + (size_t)NN * CDIM;  // [NN, HDIM] state lives in d_out tail

  char* ws = (char*)d_ws;
  size_t off = 0;
  auto alloc = [&](size_t bytes) -> void* {
    void* p = ws + off;
    off = (off + bytes + 255) & ~(size_t)255;
    return p;
  };
  float* Y         = (float*)alloc((size_t)NN * HDIM * 4);
  float* csr_coef  = (float*)alloc((size_t)NE * 4);
  float* dinv      = (float*)alloc((size_t)NN * 4);
  float* h3        = (float*)alloc((size_t)NN * CDIM * 4);
  int*   cnt       = (int*)alloc((size_t)NN * 4);
  int*   fill      = (int*)alloc((size_t)NN * 4);
  int*   row_start = (int*)alloc((size_t)(NN + 1) * 4);
  int*   csr_src   = (int*)alloc((size_t)NE * 4);

  const int* src = ei;
  const int* dst = ei + NE;

  // setup (once per call; reused by all 14 layers)
  k_zero_i32<<<(NN + 255) / 256, 256, 0, stream>>>(cnt, NN);
  k_zero_i32<<<(NN + 255) / 256, 256, 0, stream>>>(fill, NN);
  k_hist<<<(NE + 255) / 256, 256, 0, stream>>>(dst, cnt);
  k_dinv<<<(NN + 255) / 256, 256, 0, stream>>>(cnt, dinv);
  k_scan<<<1, 1024, 0, stream>>>(cnt, row_start);
  k_fill<<<(NE + 255) / 256, 256, 0, stream>>>(src, dst, row_start, fill, dinv, csr_src, csr_coef);

  dim3 gemm_grid((NN + BM - 1) / BM, HDIM / BN);
  int agg_grid = (NN + 3) / 4;

  // conv0: x[N,256] @ W0 -> Y; aggregate -> X (pre-relu stored; relu applied on next read)
  k_gemm<<<gemm_grid, 256, 0, stream>>>(x, W0, Y, NN, FDIM, 0);
  k_agg<<<agg_grid, 256, 0, stream>>>(Y, X, row_start, csr_src, csr_coef, dinv, b0);

  // 6 residual blocks x 2 convs, all H->H, relu fused on A-load
  for (int ib = 0; ib < NBLK; ++ib) {
    for (int j = 0; j < 2; ++j) {
      const float* W  = Wr + (size_t)(ib * 2 + j) * HDIM * HDIM;
      const float* bb = br + (size_t)(ib * 2 + j) * HDIM;
      k_gemm<<<gemm_grid, 256, 0, stream>>>(X, W, Y, NN, HDIM, 1);
      k_agg<<<agg_grid, 256, 0, stream>>>(Y, X, row_start, csr_src, csr_coef, dinv, bb);
    }
  }

  // materialize final relu'd x in-place (this IS output 1), then final conv -> out[N,3]
  k_relu4<<<(NN * HDIM / 4 + 255) / 256, 256, 0, stream>>>(X, NN * HDIM / 4);
  k_gemm3<<<(NN + 3) / 4, 256, 0, stream>>>(X, W1, h3);
  k_agg3<<<(NN + 255) / 256, 256, 0, stream>>>(h3, out, row_start, csr_src, csr_coef, dinv, b1);
}

// Round 2
// 3492.776 us; speedup vs baseline: 1.7559x; 1.7559x over previous
//
#include <hip/hip_runtime.h>
#include <cstdint>
#include <cstddef>

#define NN   50000
#define NE   400000
#define FDIM 256
#define HDIM 512
#define CDIM 3
#define NBLK 6

typedef __attribute__((ext_vector_type(4))) float f4;
typedef __attribute__((ext_vector_type(4))) float f32x4;
typedef _Float16 half8 __attribute__((ext_vector_type(8)));
typedef _Float16 half4 __attribute__((ext_vector_type(4)));

// ---------------- setup kernels ----------------

__global__ __launch_bounds__(256) void k_zero_i32(int* p, int n) {
  int i = blockIdx.x * 256 + threadIdx.x;
  if (i < n) p[i] = 0;
}

__global__ __launch_bounds__(256) void k_hist(const int* __restrict__ dst, int* __restrict__ cnt) {
  int e = blockIdx.x * 256 + threadIdx.x;
  if (e < NE) {
    int d = dst[e];
    if ((unsigned)d < (unsigned)NN) atomicAdd(&cnt[d], 1);
  }
}

__global__ __launch_bounds__(256) void k_dinv(const int* __restrict__ cnt, float* __restrict__ dinv) {
  int i = blockIdx.x * 256 + threadIdx.x;
  if (i < NN) dinv[i] = rsqrtf((float)cnt[i] + 1.0f);
}

// single-block exclusive scan of cnt[NN] -> row_start[NN+1]
__global__ __launch_bounds__(1024) void k_scan(const int* __restrict__ cnt, int* __restrict__ row_start) {
  __shared__ int wsum[16];
  __shared__ int carry_s;
  int tid = threadIdx.x, lane = tid & 63, wid = tid >> 6;
  if (tid == 0) carry_s = 0;
  __syncthreads();
  for (int base = 0; base < NN; base += 1024) {
    int i = base + tid;
    int v = (i < NN) ? cnt[i] : 0;
    int incl = v;
#pragma unroll
    for (int off = 1; off < 64; off <<= 1) {
      int t = __shfl_up(incl, off);
      if (lane >= off) incl += t;
    }
    if (lane == 63) wsum[wid] = incl;
    __syncthreads();
    int woff = 0;
    for (int w = 0; w < wid; ++w) woff += wsum[w];
    int excl = carry_s + woff + (incl - v);
    if (i < NN) row_start[i] = excl;
    __syncthreads();
    if (tid == 1023) carry_s = excl + v;
    __syncthreads();
  }
  if (threadIdx.x == 0) row_start[NN] = carry_s;
}

__global__ __launch_bounds__(256) void k_fill(const int* __restrict__ src, const int* __restrict__ dst,
    const int* __restrict__ row_start, int* __restrict__ fill,
    const float* __restrict__ dinv, int* __restrict__ csr_src, float* __restrict__ csr_coef) {
  int e = blockIdx.x * 256 + threadIdx.x;
  if (e >= NE) return;
  int s = src[e], d = dst[e];
  if ((unsigned)s >= (unsigned)NN || (unsigned)d >= (unsigned)NN) return;
  int pos = row_start[d] + atomicAdd(&fill[d], 1);
  csr_src[pos] = s;
  csr_coef[pos] = dinv[s] * dinv[d];
}

// ---------------- conversion kernels ----------------

// x [N,256] fp32 -> hi/lo fp16 (no relu, no transpose)
__global__ __launch_bounds__(256) void k_cvt_x(const float* __restrict__ x,
    _Float16* __restrict__ xhi, _Float16* __restrict__ xlo, int n4) {
  int i = blockIdx.x * 256 + threadIdx.x;
  if (i >= n4) return;
  f4 v = ((const f4*)x)[i];
  half4 h, l;
#pragma unroll
  for (int c = 0; c < 4; ++c) {
    float vv = v[c];
    _Float16 hh = (_Float16)vv;
    h[c] = hh;
    l[c] = (_Float16)(vv - (float)hh);
  }
  ((half4*)xhi)[i] = h;
  ((half4*)xlo)[i] = l;
}

// W [K,N] fp32 -> transposed hi/lo fp16 [N,K]  (z = matrix index)
__global__ __launch_bounds__(256) void k_cvt_wt(const float* __restrict__ W,
    _Float16* __restrict__ Whi, _Float16* __restrict__ Wlo, int K, int N) {
  __shared__ float tile[32][33];
  int l = blockIdx.z;
  const float* Wl = W + (size_t)l * K * N;
  _Float16* Oh = Whi + (size_t)l * K * N;
  _Float16* Ol = Wlo + (size_t)l * K * N;
  int k0 = blockIdx.x * 32, n0 = blockIdx.y * 32;
  int tx = threadIdx.x & 31, ty = threadIdx.x >> 5;
#pragma unroll
  for (int p = 0; p < 4; ++p)
    tile[ty + 8 * p][tx] = Wl[(size_t)(k0 + ty + 8 * p) * N + n0 + tx];
  __syncthreads();
#pragma unroll
  for (int p = 0; p < 4; ++p) {
    int n = n0 + ty + 8 * p, k = k0 + tx;
    float v = tile[tx][ty + 8 * p];
    _Float16 hi = (_Float16)v;
    Oh[(size_t)n * K + k] = hi;
    Ol[(size_t)n * K + k] = (_Float16)(v - (float)hi);
  }
}

// ---------------- MFMA GEMM: C[M,512] = (Ahi+Alo)[M,K] @ (Bhi+Blo)^T ----------------
// A: [M,K] fp16 hi/lo; B: [N,K] fp16 hi/lo (pre-transposed, k-contiguous)
// fp32-accurate via 3-term split: ah*bh + ah*bl + al*bh

#define LDK 40  // 32 + 8 pad: b128 frag reads land 2-way/bank (free)

__global__ __launch_bounds__(256) void k_gemm16(
    const _Float16* __restrict__ Ahi, const _Float16* __restrict__ Alo,
    const _Float16* __restrict__ Bhi, const _Float16* __restrict__ Blo,
    float* __restrict__ C, int M, int K) {
  __shared__ _Float16 As[2][128][LDK];
  __shared__ _Float16 Bs[2][128][LDK];
  const int tid = threadIdx.x;
  const int lane = tid & 63, wave = tid >> 6;
  const int wm = wave & 1, wn = wave >> 1;
  const int quad = lane >> 4, r = lane & 15;
  const int row0 = blockIdx.x * 128, col0 = blockIdx.y * 128;

  f32x4 acc[4][4];
#pragma unroll
  for (int i = 0; i < 4; ++i)
#pragma unroll
    for (int j = 0; j < 4; ++j) acc[i][j] = (f32x4){0.f, 0.f, 0.f, 0.f};

  for (int k0 = 0; k0 < K; k0 += 32) {
    // stage A & B tiles (hi + lo) : 128 rows x 32 k each
#pragma unroll
    for (int j = 0; j < 2; ++j) {
      int c = tid + j * 256;
      int rrow = c >> 2, kc = (c & 3) * 8;
      int grow = row0 + rrow;
      half8 vh = {}, vl = {};
      if (grow < M) {
        vh = *(const half8*)(Ahi + (size_t)grow * K + k0 + kc);
        vl = *(const half8*)(Alo + (size_t)grow * K + k0 + kc);
      }
      *(half8*)&As[0][rrow][kc] = vh;
      *(half8*)&As[1][rrow][kc] = vl;
      int gn = col0 + rrow;
      *(half8*)&Bs[0][rrow][kc] = *(const half8*)(Bhi + (size_t)gn * K + k0 + kc);
      *(half8*)&Bs[1][rrow][kc] = *(const half8*)(Blo + (size_t)gn * K + k0 + kc);
    }
    __syncthreads();

    half8 ah[4], al[4], bh[4], bl[4];
#pragma unroll
    for (int mi = 0; mi < 4; ++mi) {
      int mrow = wm * 64 + mi * 16 + r;
      ah[mi] = *(const half8*)&As[0][mrow][quad * 8];
      al[mi] = *(const half8*)&As[1][mrow][quad * 8];
    }
#pragma unroll
    for (int ni = 0; ni < 4; ++ni) {
      int nrow = wn * 64 + ni * 16 + r;
      bh[ni] = *(const half8*)&Bs[0][nrow][quad * 8];
      bl[ni] = *(const half8*)&Bs[1][nrow][quad * 8];
    }
#pragma unroll
    for (int mi = 0; mi < 4; ++mi)
#pragma unroll
      for (int ni = 0; ni < 4; ++ni) {
        acc[mi][ni] = __builtin_amdgcn_mfma_f32_16x16x32_f16(ah[mi], bh[ni], acc[mi][ni], 0, 0, 0);
        acc[mi][ni] = __builtin_amdgcn_mfma_f32_16x16x32_f16(ah[mi], bl[ni], acc[mi][ni], 0, 0, 0);
        acc[mi][ni] = __builtin_amdgcn_mfma_f32_16x16x32_f16(al[mi], bh[ni], acc[mi][ni], 0, 0, 0);
      }
    __syncthreads();
  }

  // epilogue: C/D layout col=lane&15, row=quad*4+reg
#pragma unroll
  for (int mi = 0; mi < 4; ++mi)
#pragma unroll
    for (int reg = 0; reg < 4; ++reg) {
      int grow = row0 + wm * 64 + mi * 16 + quad * 4 + reg;
      if (grow < M) {
#pragma unroll
        for (int ni = 0; ni < 4; ++ni)
          C[(size_t)grow * HDIM + col0 + wn * 64 + ni * 16 + r] = acc[mi][ni][reg];
      }
    }
}

// ---------------- CSR aggregation ----------------
// xrelu = relu(b + dinv_i^2*h_i + sum coef*h_src); emit fp16 hi/lo (+ optional fp32)

__global__ __launch_bounds__(256) void k_agg(const float* __restrict__ h,
    _Float16* __restrict__ xhi, _Float16* __restrict__ xlo, float* __restrict__ xf,
    const int* __restrict__ row_start, const int* __restrict__ csr_src,
    const float* __restrict__ csr_coef, const float* __restrict__ dinv,
    const float* __restrict__ bias) {
  int wid = threadIdx.x >> 6, lane = threadIdx.x & 63;
  int i = blockIdx.x * 4 + wid;
  if (i >= NN) return;
  int c0 = lane * 4, c1 = 256 + lane * 4;
  float di = dinv[i];
  float d2 = di * di;
  const float* hi_ = h + (size_t)i * HDIM;
  f4 acc0 = *(const f4*)(hi_ + c0) * d2;
  f4 acc1 = *(const f4*)(hi_ + c1) * d2;
  int e0 = row_start[i], e1 = row_start[i + 1];
  for (int e = e0; e < e1; ++e) {
    int s = csr_src[e];
    float c = csr_coef[e];
    const float* hs = h + (size_t)s * HDIM;
    acc0 += *(const f4*)(hs + c0) * c;
    acc1 += *(const f4*)(hs + c1) * c;
  }
  acc0 += *(const f4*)(bias + c0);
  acc1 += *(const f4*)(bias + c1);
  // relu
#pragma unroll
  for (int c = 0; c < 4; ++c) { acc0[c] = fmaxf(acc0[c], 0.f); acc1[c] = fmaxf(acc1[c], 0.f); }
  half4 h0, l0, h1, l1;
#pragma unroll
  for (int c = 0; c < 4; ++c) {
    _Float16 hh0 = (_Float16)acc0[c]; h0[c] = hh0; l0[c] = (_Float16)(acc0[c] - (float)hh0);
    _Float16 hh1 = (_Float16)acc1[c]; h1[c] = hh1; l1[c] = (_Float16)(acc1[c] - (float)hh1);
  }
  *(half4*)(xhi + (size_t)i * HDIM + c0) = h0;
  *(half4*)(xhi + (size_t)i * HDIM + c1) = h1;
  *(half4*)(xlo + (size_t)i * HDIM + c0) = l0;
  *(half4*)(xlo + (size_t)i * HDIM + c1) = l1;
  if (xf) {
    *(f4*)(xf + (size_t)i * HDIM + c0) = acc0;
    *(f4*)(xf + (size_t)i * HDIM + c1) = acc1;
  }
}

// final conv: h3[N,3] = X[N,512] @ W1[512,3]; one wave per node
__global__ __launch_bounds__(256) void k_gemm3(const float* __restrict__ X, const float* __restrict__ W1,
    float* __restrict__ h3) {
  int wid = threadIdx.x >> 6, lane = threadIdx.x & 63;
  int i = blockIdx.x * 4 + wid;
  if (i >= NN) return;
  const float* xi = X + (size_t)i * HDIM;
  float a0 = 0.f, a1 = 0.f, a2 = 0.f;
#pragma unroll
  for (int t = 0; t < HDIM / 64; ++t) {
    int k = t * 64 + lane;
    float v = xi[k];
    a0 = fmaf(v, W1[k * 3 + 0], a0);
    a1 = fmaf(v, W1[k * 3 + 1], a1);
    a2 = fmaf(v, W1[k * 3 + 2], a2);
  }
#pragma unroll
  for (int off = 32; off > 0; off >>= 1) {
    a0 += __shfl_down(a0, off);
    a1 += __shfl_down(a1, off);
    a2 += __shfl_down(a2, off);
  }
  if (lane == 0) {
    h3[(size_t)i * 3 + 0] = a0;
    h3[(size_t)i * 3 + 1] = a1;
    h3[(size_t)i * 3 + 2] = a2;
  }
}

__global__ __launch_bounds__(256) void k_agg3(const float* __restrict__ h3, float* __restrict__ out,
    const int* __restrict__ row_start, const int* __restrict__ csr_src,
    const float* __restrict__ csr_coef, const float* __restrict__ dinv,
    const float* __restrict__ b1) {
  int i = blockIdx.x * 256 + threadIdx.x;
  if (i >= NN) return;
  float d2 = dinv[i] * dinv[i];
  float o0 = h3[(size_t)i * 3 + 0] * d2;
  float o1 = h3[(size_t)i * 3 + 1] * d2;
  float o2 = h3[(size_t)i * 3 + 2] * d2;
  int e0 = row_start[i], e1 = row_start[i + 1];
  for (int e = e0; e < e1; ++e) {
    int s = csr_src[e];
    float c = csr_coef[e];
    o0 = fmaf(c, h3[(size_t)s * 3 + 0], o0);
    o1 = fmaf(c, h3[(size_t)s * 3 + 1], o1);
    o2 = fmaf(c, h3[(size_t)s * 3 + 2], o2);
  }
  out[(size_t)i * 3 + 0] = o0 + b1[0];
  out[(size_t)i * 3 + 1] = o1 + b1[1];
  out[(size_t)i * 3 + 2] = o2 + b1[2];
}

// ---------------- launch ----------------

extern "C" void kernel_launch(void* const* d_in, const int* in_sizes, int n_in,
                              void* d_out, int out_size, void* d_ws, size_t ws_size,
                              hipStream_t stream) {
  const float* x  = (const float*)d_in[0];
  const int*   ei = (const int*)d_in[1];
  const float* W0 = (const float*)d_in[2];
  const float* b0 = (const float*)d_in[3];
  const float* Wr = (const float*)d_in[4];
  const float* br = (const float*)d_in[5];
  const float* W1 = (const float*)d_in[6];
  const float* b1 = (const float*)d_in[7];
  float* out = (float*)d_out;
  float* X = out + (size_t)NN * CDIM;  // final relu'd state [NN, HDIM] == output 1

  char* ws = (char*)d_ws;
  size_t off = 0;
  auto alloc = [&](size_t bytes) -> void* {
    void* p = ws + off;
    off = (off + bytes + 255) & ~(size_t)255;
    return p;
  };
  float*     Y      = (float*)alloc((size_t)NN * HDIM * 4);        // 102.4 MB
  _Float16*  Xhi    = (_Float16*)alloc((size_t)NN * HDIM * 2);     // 51.2 MB
  _Float16*  Xlo    = (_Float16*)alloc((size_t)NN * HDIM * 2);     // 51.2 MB
  _Float16*  W0thi  = (_Float16*)alloc((size_t)FDIM * HDIM * 2);
  _Float16*  W0tlo  = (_Float16*)alloc((size_t)FDIM * HDIM * 2);
  _Float16*  Wrthi  = (_Float16*)alloc((size_t)NBLK * 2 * HDIM * HDIM * 2);
  _Float16*  Wrtlo  = (_Float16*)alloc((size_t)NBLK * 2 * HDIM * HDIM * 2);
  float*     csr_coef = (float*)alloc((size_t)NE * 4);
  float*     dinv     = (float*)alloc((size_t)NN * 4);
  float*     h3       = (float*)alloc((size_t)NN * CDIM * 4);
  int*       cnt      = (int*)alloc((size_t)NN * 4);
  int*       fill     = (int*)alloc((size_t)NN * 4);
  int*       row_start= (int*)alloc((size_t)(NN + 1) * 4);
  int*       csr_src  = (int*)alloc((size_t)NE * 4);

  const int* src = ei;
  const int* dst = ei + NE;

  // ---- setup (once per call; reused by all 14 layers) ----
  k_zero_i32<<<(NN + 255) / 256, 256, 0, stream>>>(cnt, NN);
  k_zero_i32<<<(NN + 255) / 256, 256, 0, stream>>>(fill, NN);
  k_hist<<<(NE + 255) / 256, 256, 0, stream>>>(dst, cnt);
  k_dinv<<<(NN + 255) / 256, 256, 0, stream>>>(cnt, dinv);
  k_scan<<<1, 1024, 0, stream>>>(cnt, row_start);
  k_fill<<<(NE + 255) / 256, 256, 0, stream>>>(src, dst, row_start, fill, dinv, csr_src, csr_coef);

  // weight + input conversion (hi/lo fp16, weights transposed to [N][K])
  k_cvt_x<<<(NN * FDIM / 4 + 255) / 256, 256, 0, stream>>>(x, Xhi, Xlo, NN * FDIM / 4);
  {
    dim3 g0(FDIM / 32, HDIM / 32, 1);
    k_cvt_wt<<<g0, 256, 0, stream>>>(W0, W0thi, W0tlo, FDIM, HDIM);
    dim3 gr(HDIM / 32, HDIM / 32, NBLK * 2);
    k_cvt_wt<<<gr, 256, 0, stream>>>(Wr, Wrthi, Wrtlo, HDIM, HDIM);
  }

  dim3 gemm_grid((NN + 127) / 128, HDIM / 128);
  int agg_grid = (NN + 3) / 4;

  // conv0: (x0 hi/lo live in the head of Xhi/Xlo; consumed before agg overwrites)
  k_gemm16<<<gemm_grid, 256, 0, stream>>>(Xhi, Xlo, W0thi, W0tlo, Y, NN, FDIM);
  k_agg<<<agg_grid, 256, 0, stream>>>(Y, Xhi, Xlo, nullptr, row_start, csr_src, csr_coef, dinv, b0);

  // 6 residual blocks x 2 convs, all H->H
  for (int ib = 0; ib < NBLK; ++ib) {
    for (int j = 0; j < 2; ++j) {
      int li = ib * 2 + j;
      const _Float16* Wh = Wrthi + (size_t)li * HDIM * HDIM;
      const _Float16* Wl = Wrtlo + (size_t)li * HDIM * HDIM;
      const float* bb = br + (size_t)li * HDIM;
      bool last = (ib == NBLK - 1) && (j == 1);
      k_gemm16<<<gemm_grid, 256, 0, stream>>>(Xhi, Xlo, Wh, Wl, Y, NN, HDIM);
      k_agg<<<agg_grid, 256, 0, stream>>>(Y, Xhi, Xlo, last ? X : nullptr,
                                          row_start, csr_src, csr_coef, dinv, bb);
    }
  }

  // final conv: X (relu'd, fp32) @ W1 -> out[N,3]
  k_gemm3<<<(NN + 3) / 4, 256, 0, stream>>>(X, W1, h3);
  k_agg3<<<(NN + 255) / 256, 256, 0, stream>>>(h3, out, row_start, csr_src, csr_coef, dinv, b1);
}

// Round 3
// 3394.839 us; speedup vs baseline: 1.8066x; 1.0288x over previous
//
#include <hip/hip_runtime.h>
#include <cstdint>
#include <cstddef>

#define NN   50000
#define NE   400000
#define FDIM 256
#define HDIM 512
#define CDIM 3
#define NBLK 6

typedef __attribute__((ext_vector_type(4))) float f4;
typedef __attribute__((ext_vector_type(4))) float f32x4;
typedef _Float16 half8 __attribute__((ext_vector_type(8)));
typedef _Float16 half4 __attribute__((ext_vector_type(4)));

// ---------------- setup kernels ----------------

__global__ __launch_bounds__(256) void k_zero_i32(int* p, int n) {
  int i = blockIdx.x * 256 + threadIdx.x;
  if (i < n) p[i] = 0;
}

__global__ __launch_bounds__(256) void k_hist(const int* __restrict__ dst, int* __restrict__ cnt) {
  int e = blockIdx.x * 256 + threadIdx.x;
  if (e < NE) {
    int d = dst[e];
    if ((unsigned)d < (unsigned)NN) atomicAdd(&cnt[d], 1);
  }
}

__global__ __launch_bounds__(256) void k_dinv(const int* __restrict__ cnt, float* __restrict__ dinv) {
  int i = blockIdx.x * 256 + threadIdx.x;
  if (i < NN) dinv[i] = rsqrtf((float)cnt[i] + 1.0f);
}

// single-block exclusive scan of cnt[NN] -> row_start[NN+1]
__global__ __launch_bounds__(1024) void k_scan(const int* __restrict__ cnt, int* __restrict__ row_start) {
  __shared__ int wsum[16];
  __shared__ int carry_s;
  int tid = threadIdx.x, lane = tid & 63, wid = tid >> 6;
  if (tid == 0) carry_s = 0;
  __syncthreads();
  for (int base = 0; base < NN; base += 1024) {
    int i = base + tid;
    int v = (i < NN) ? cnt[i] : 0;
    int incl = v;
#pragma unroll
    for (int off = 1; off < 64; off <<= 1) {
      int t = __shfl_up(incl, off);
      if (lane >= off) incl += t;
    }
    if (lane == 63) wsum[wid] = incl;
    __syncthreads();
    int woff = 0;
    for (int w = 0; w < wid; ++w) woff += wsum[w];
    int excl = carry_s + woff + (incl - v);
    if (i < NN) row_start[i] = excl;
    __syncthreads();
    if (tid == 1023) carry_s = excl + v;
    __syncthreads();
  }
  if (threadIdx.x == 0) row_start[NN] = carry_s;
}

__global__ __launch_bounds__(256) void k_fill(const int* __restrict__ src, const int* __restrict__ dst,
    const int* __restrict__ row_start, int* __restrict__ fill,
    const float* __restrict__ dinv, int* __restrict__ csr_src, float* __restrict__ csr_coef) {
  int e = blockIdx.x * 256 + threadIdx.x;
  if (e >= NE) return;
  int s = src[e], d = dst[e];
  if ((unsigned)s >= (unsigned)NN || (unsigned)d >= (unsigned)NN) return;
  int pos = row_start[d] + atomicAdd(&fill[d], 1);
  csr_src[pos] = s;
  csr_coef[pos] = dinv[s] * dinv[d];
}

// ---------------- conversion kernels ----------------

// x [N,256] fp32 -> hi/lo fp16 (no relu, no transpose)
__global__ __launch_bounds__(256) void k_cvt_x(const float* __restrict__ x,
    _Float16* __restrict__ xhi, _Float16* __restrict__ xlo, int n4) {
  int i = blockIdx.x * 256 + threadIdx.x;
  if (i >= n4) return;
  f4 v = ((const f4*)x)[i];
  half4 h, l;
#pragma unroll
  for (int c = 0; c < 4; ++c) {
    float vv = v[c];
    _Float16 hh = (_Float16)vv;
    h[c] = hh;
    l[c] = (_Float16)(vv - (float)hh);
  }
  ((half4*)xhi)[i] = h;
  ((half4*)xlo)[i] = l;
}

// W [K,N] fp32 -> transposed hi/lo fp16 [N,K]  (z = matrix index)
__global__ __launch_bounds__(256) void k_cvt_wt(const float* __restrict__ W,
    _Float16* __restrict__ Whi, _Float16* __restrict__ Wlo, int K, int N) {
  __shared__ float tile[32][33];
  int l = blockIdx.z;
  const float* Wl = W + (size_t)l * K * N;
  _Float16* Oh = Whi + (size_t)l * K * N;
  _Float16* Ol = Wlo + (size_t)l * K * N;
  int k0 = blockIdx.x * 32, n0 = blockIdx.y * 32;
  int tx = threadIdx.x & 31, ty = threadIdx.x >> 5;
#pragma unroll
  for (int p = 0; p < 4; ++p)
    tile[ty + 8 * p][tx] = Wl[(size_t)(k0 + ty + 8 * p) * N + n0 + tx];
  __syncthreads();
#pragma unroll
  for (int p = 0; p < 4; ++p) {
    int n = n0 + ty + 8 * p, k = k0 + tx;
    float v = tile[tx][ty + 8 * p];
    _Float16 hi = (_Float16)v;
    Oh[(size_t)n * K + k] = hi;
    Ol[(size_t)n * K + k] = (_Float16)(v - (float)hi);
  }
}

// ---------------- MFMA GEMM: C[M,512] = (Ahi+Alo)[M,K] @ (Bhi+Blo)^T ----------------
// A: [M,K] fp16 hi/lo; B: [N,K] fp16 hi/lo (pre-transposed, k-contiguous)
// fp32-accurate via 3-term split: ah*bh + ah*bl + al*bh

#define LDK 40  // 32 + 8 pad: b128 frag reads land 2-way/bank (free)

__global__ __launch_bounds__(256) void k_gemm16(
    const _Float16* __restrict__ Ahi, const _Float16* __restrict__ Alo,
    const _Float16* __restrict__ Bhi, const _Float16* __restrict__ Blo,
    float* __restrict__ C, int M, int K) {
  __shared__ _Float16 As[2][128][LDK];
  __shared__ _Float16 Bs[2][128][LDK];
  const int tid = threadIdx.x;
  const int lane = tid & 63, wave = tid >> 6;
  const int wm = wave & 1, wn = wave >> 1;
  const int quad = lane >> 4, r = lane & 15;
  const int row0 = blockIdx.x * 128, col0 = blockIdx.y * 128;

  f32x4 acc[4][4];
#pragma unroll
  for (int i = 0; i < 4; ++i)
#pragma unroll
    for (int j = 0; j < 4; ++j) acc[i][j] = (f32x4){0.f, 0.f, 0.f, 0.f};

  for (int k0 = 0; k0 < K; k0 += 32) {
    // stage A & B tiles (hi + lo) : 128 rows x 32 k each
#pragma unroll
    for (int j = 0; j < 2; ++j) {
      int c = tid + j * 256;
      int rrow = c >> 2, kc = (c & 3) * 8;
      int grow = row0 + rrow;
      half8 vh = {}, vl = {};
      if (grow < M) {
        vh = *(const half8*)(Ahi + (size_t)grow * K + k0 + kc);
        vl = *(const half8*)(Alo + (size_t)grow * K + k0 + kc);
      }
      *(half8*)&As[0][rrow][kc] = vh;
      *(half8*)&As[1][rrow][kc] = vl;
      int gn = col0 + rrow;
      *(half8*)&Bs[0][rrow][kc] = *(const half8*)(Bhi + (size_t)gn * K + k0 + kc);
      *(half8*)&Bs[1][rrow][kc] = *(const half8*)(Blo + (size_t)gn * K + k0 + kc);
    }
    __syncthreads();

    half8 ah[4], al[4], bh[4], bl[4];
#pragma unroll
    for (int mi = 0; mi < 4; ++mi) {
      int mrow = wm * 64 + mi * 16 + r;
      ah[mi] = *(const half8*)&As[0][mrow][quad * 8];
      al[mi] = *(const half8*)&As[1][mrow][quad * 8];
    }
#pragma unroll
    for (int ni = 0; ni < 4; ++ni) {
      int nrow = wn * 64 + ni * 16 + r;
      bh[ni] = *(const half8*)&Bs[0][nrow][quad * 8];
      bl[ni] = *(const half8*)&Bs[1][nrow][quad * 8];
    }
#pragma unroll
    for (int mi = 0; mi < 4; ++mi)
#pragma unroll
      for (int ni = 0; ni < 4; ++ni) {
        acc[mi][ni] = __builtin_amdgcn_mfma_f32_16x16x32_f16(ah[mi], bh[ni], acc[mi][ni], 0, 0, 0);
        acc[mi][ni] = __builtin_amdgcn_mfma_f32_16x16x32_f16(ah[mi], bl[ni], acc[mi][ni], 0, 0, 0);
        acc[mi][ni] = __builtin_amdgcn_mfma_f32_16x16x32_f16(al[mi], bh[ni], acc[mi][ni], 0, 0, 0);
      }
    __syncthreads();
  }

  // epilogue: C/D layout col=lane&15, row=quad*4+reg
#pragma unroll
  for (int mi = 0; mi < 4; ++mi)
#pragma unroll
    for (int reg = 0; reg < 4; ++reg) {
      int grow = row0 + wm * 64 + mi * 16 + quad * 4 + reg;
      if (grow < M) {
#pragma unroll
        for (int ni = 0; ni < 4; ++ni)
          C[(size_t)grow * HDIM + col0 + wn * 64 + ni * 16 + r] = acc[mi][ni][reg];
      }
    }
}

// ---------------- CSR aggregation (feature-panel split for L3 residency) ----------------
// Panel p = blockIdx.y covers features [p*256, p*256+256). Gather working set per
// panel = 50048*256*4B = 51 MB << 256 MB L3, so neighbor rows hit Infinity Cache.
// xrelu = relu(b + dinv_i^2*h_i + sum coef*h_src); emit fp16 hi/lo (+ optional fp32)

__global__ __launch_bounds__(256) void k_agg(const float* __restrict__ h,
    _Float16* __restrict__ xhi, _Float16* __restrict__ xlo, float* __restrict__ xf,
    const int* __restrict__ row_start, const int* __restrict__ csr_src,
    const float* __restrict__ csr_coef, const float* __restrict__ dinv,
    const float* __restrict__ bias) {
  int wid = threadIdx.x >> 6, lane = threadIdx.x & 63;
  int i = blockIdx.x * 4 + wid;
  if (i >= NN) return;
  int c = blockIdx.y * 256 + lane * 4;
  float di = dinv[i];
  float d2 = di * di;
  f4 acc = *(const f4*)(h + (size_t)i * HDIM + c) * d2;
  int e0 = row_start[i], e1 = row_start[i + 1];
  for (int e = e0; e < e1; ++e) {
    int s = csr_src[e];
    float cf = csr_coef[e];
    acc += *(const f4*)(h + (size_t)s * HDIM + c) * cf;
  }
  acc += *(const f4*)(bias + c);
#pragma unroll
  for (int q = 0; q < 4; ++q) acc[q] = fmaxf(acc[q], 0.f);
  half4 hh, ll;
#pragma unroll
  for (int q = 0; q < 4; ++q) {
    _Float16 hv = (_Float16)acc[q];
    hh[q] = hv;
    ll[q] = (_Float16)(acc[q] - (float)hv);
  }
  *(half4*)(xhi + (size_t)i * HDIM + c) = hh;
  *(half4*)(xlo + (size_t)i * HDIM + c) = ll;
  if (xf) *(f4*)(xf + (size_t)i * HDIM + c) = acc;
}

// final conv: h3[N,3] = X[N,512] @ W1[512,3]; one wave per node
__global__ __launch_bounds__(256) void k_gemm3(const float* __restrict__ X, const float* __restrict__ W1,
    float* __restrict__ h3) {
  int wid = threadIdx.x >> 6, lane = threadIdx.x & 63;
  int i = blockIdx.x * 4 + wid;
  if (i >= NN) return;
  const float* xi = X + (size_t)i * HDIM;
  float a0 = 0.f, a1 = 0.f, a2 = 0.f;
#pragma unroll
  for (int t = 0; t < HDIM / 64; ++t) {
    int k = t * 64 + lane;
    float v = xi[k];
    a0 = fmaf(v, W1[k * 3 + 0], a0);
    a1 = fmaf(v, W1[k * 3 + 1], a1);
    a2 = fmaf(v, W1[k * 3 + 2], a2);
  }
#pragma unroll
  for (int off = 32; off > 0; off >>= 1) {
    a0 += __shfl_down(a0, off);
    a1 += __shfl_down(a1, off);
    a2 += __shfl_down(a2, off);
  }
  if (lane == 0) {
    h3[(size_t)i * 3 + 0] = a0;
    h3[(size_t)i * 3 + 1] = a1;
    h3[(size_t)i * 3 + 2] = a2;
  }
}

__global__ __launch_bounds__(256) void k_agg3(const float* __restrict__ h3, float* __restrict__ out,
    const int* __restrict__ row_start, const int* __restrict__ csr_src,
    const float* __restrict__ csr_coef, const float* __restrict__ dinv,
    const float* __restrict__ b1) {
  int i = blockIdx.x * 256 + threadIdx.x;
  if (i >= NN) return;
  float d2 = dinv[i] * dinv[i];
  float o0 = h3[(size_t)i * 3 + 0] * d2;
  float o1 = h3[(size_t)i * 3 + 1] * d2;
  float o2 = h3[(size_t)i * 3 + 2] * d2;
  int e0 = row_start[i], e1 = row_start[i + 1];
  for (int e = e0; e < e1; ++e) {
    int s = csr_src[e];
    float c = csr_coef[e];
    o0 = fmaf(c, h3[(size_t)s * 3 + 0], o0);
    o1 = fmaf(c, h3[(size_t)s * 3 + 1], o1);
    o2 = fmaf(c, h3[(size_t)s * 3 + 2], o2);
  }
  out[(size_t)i * 3 + 0] = o0 + b1[0];
  out[(size_t)i * 3 + 1] = o1 + b1[1];
  out[(size_t)i * 3 + 2] = o2 + b1[2];
}

// ---------------- launch ----------------

extern "C" void kernel_launch(void* const* d_in, const int* in_sizes, int n_in,
                              void* d_out, int out_size, void* d_ws, size_t ws_size,
                              hipStream_t stream) {
  const float* x  = (const float*)d_in[0];
  const int*   ei = (const int*)d_in[1];
  const float* W0 = (const float*)d_in[2];
  const float* b0 = (const float*)d_in[3];
  const float* Wr = (const float*)d_in[4];
  const float* br = (const float*)d_in[5];
  const float* W1 = (const float*)d_in[6];
  const float* b1 = (const float*)d_in[7];
  float* out = (float*)d_out;
  float* X = out + (size_t)NN * CDIM;  // final relu'd state [NN, HDIM] == output 1

  char* ws = (char*)d_ws;
  size_t off = 0;
  auto alloc = [&](size_t bytes) -> void* {
    void* p = ws + off;
    off = (off + bytes + 255) & ~(size_t)255;
    return p;
  };
  float*     Y      = (float*)alloc((size_t)NN * HDIM * 4);        // 102.4 MB
  _Float16*  Xhi    = (_Float16*)alloc((size_t)NN * HDIM * 2);     // 51.2 MB
  _Float16*  Xlo    = (_Float16*)alloc((size_t)NN * HDIM * 2);     // 51.2 MB
  _Float16*  W0thi  = (_Float16*)alloc((size_t)FDIM * HDIM * 2);
  _Float16*  W0tlo  = (_Float16*)alloc((size_t)FDIM * HDIM * 2);
  _Float16*  Wrthi  = (_Float16*)alloc((size_t)NBLK * 2 * HDIM * HDIM * 2);
  _Float16*  Wrtlo  = (_Float16*)alloc((size_t)NBLK * 2 * HDIM * HDIM * 2);
  float*     csr_coef = (float*)alloc((size_t)NE * 4);
  float*     dinv     = (float*)alloc((size_t)NN * 4);
  float*     h3       = (float*)alloc((size_t)NN * CDIM * 4);
  int*       cnt      = (int*)alloc((size_t)NN * 4);
  int*       fill     = (int*)alloc((size_t)NN * 4);
  int*       row_start= (int*)alloc((size_t)(NN + 1) * 4);
  int*       csr_src  = (int*)alloc((size_t)NE * 4);

  const int* src = ei;
  const int* dst = ei + NE;

  // ---- setup (once per call; reused by all 14 layers) ----
  k_zero_i32<<<(NN + 255) / 256, 256, 0, stream>>>(cnt, NN);
  k_zero_i32<<<(NN + 255) / 256, 256, 0, stream>>>(fill, NN);
  k_hist<<<(NE + 255) / 256, 256, 0, stream>>>(dst, cnt);
  k_dinv<<<(NN + 255) / 256, 256, 0, stream>>>(cnt, dinv);
  k_scan<<<1, 1024, 0, stream>>>(cnt, row_start);
  k_fill<<<(NE + 255) / 256, 256, 0, stream>>>(src, dst, row_start, fill, dinv, csr_src, csr_coef);

  // weight + input conversion (hi/lo fp16, weights transposed to [N][K])
  k_cvt_x<<<(NN * FDIM / 4 + 255) / 256, 256, 0, stream>>>(x, Xhi, Xlo, NN * FDIM / 4);
  {
    dim3 g0(FDIM / 32, HDIM / 32, 1);
    k_cvt_wt<<<g0, 256, 0, stream>>>(W0, W0thi, W0tlo, FDIM, HDIM);
    dim3 gr(HDIM / 32, HDIM / 32, NBLK * 2);
    k_cvt_wt<<<gr, 256, 0, stream>>>(Wr, Wrthi, Wrtlo, HDIM, HDIM);
  }

  dim3 gemm_grid((NN + 127) / 128, HDIM / 128);
  dim3 agg_grid((NN + 3) / 4, 2);   // y = feature panel (256 feats): L3-resident gather

  // conv0: (x0 hi/lo live in the head of Xhi/Xlo; consumed before agg overwrites)
  k_gemm16<<<gemm_grid, 256, 0, stream>>>(Xhi, Xlo, W0thi, W0tlo, Y, NN, FDIM);
  k_agg<<<agg_grid, 256, 0, stream>>>(Y, Xhi, Xlo, nullptr, row_start, csr_src, csr_coef, dinv, b0);

  // 6 residual blocks x 2 convs, all H->H
  for (int ib = 0; ib < NBLK; ++ib) {
    for (int j = 0; j < 2; ++j) {
      int li = ib * 2 + j;
      const _Float16* Wh = Wrthi + (size_t)li * HDIM * HDIM;
      const _Float16* Wl = Wrtlo + (size_t)li * HDIM * HDIM;
      const float* bb = br + (size_t)li * HDIM;
      bool last = (ib == NBLK - 1) && (j == 1);
      k_gemm16<<<gemm_grid, 256, 0, stream>>>(Xhi, Xlo, Wh, Wl, Y, NN, HDIM);
      k_agg<<<agg_grid, 256, 0, stream>>>(Y, Xhi, Xlo, last ? X : nullptr,
                                          row_start, csr_src, csr_coef, dinv, bb);
    }
  }

  // final conv: X (relu'd, fp32) @ W1 -> out[N,3]
  k_gemm3<<<(NN + 3) / 4, 256, 0, stream>>>(X, W1, h3);
  k_agg3<<<(NN + 255) / 256, 256, 0, stream>>>(h3, out, row_start, csr_src, csr_coef, dinv, b1);
}

// Round 4
// 3352.714 us; speedup vs baseline: 1.8293x; 1.0126x over previous
//
#include <hip/hip_runtime.h>
#include <cstdint>
#include <cstddef>

#define NN   50000
#define NE   400000
#define FDIM 256
#define HDIM 512
#define CDIM 3
#define NBLK 6

typedef __attribute__((ext_vector_type(4))) float f4;
typedef __attribute__((ext_vector_type(4))) float f32x4;
typedef _Float16 half8 __attribute__((ext_vector_type(8)));
typedef _Float16 half4 __attribute__((ext_vector_type(4)));

template <typename T>
__device__ inline void nt_store(T* p, T v) { __builtin_nontemporal_store(v, p); }

// ---------------- setup kernels ----------------

__global__ __launch_bounds__(256) void k_zero_i32(int* p, int n) {
  int i = blockIdx.x * 256 + threadIdx.x;
  if (i < n) p[i] = 0;
}

__global__ __launch_bounds__(256) void k_hist(const int* __restrict__ dst, int* __restrict__ cnt) {
  int e = blockIdx.x * 256 + threadIdx.x;
  if (e < NE) {
    int d = dst[e];
    if ((unsigned)d < (unsigned)NN) atomicAdd(&cnt[d], 1);
  }
}

__global__ __launch_bounds__(256) void k_dinv(const int* __restrict__ cnt, float* __restrict__ dinv) {
  int i = blockIdx.x * 256 + threadIdx.x;
  if (i < NN) dinv[i] = rsqrtf((float)cnt[i] + 1.0f);
}

// single-block exclusive scan of cnt[NN] -> row_start[NN+1]
__global__ __launch_bounds__(1024) void k_scan(const int* __restrict__ cnt, int* __restrict__ row_start) {
  __shared__ int wsum[16];
  __shared__ int carry_s;
  int tid = threadIdx.x, lane = tid & 63, wid = tid >> 6;
  if (tid == 0) carry_s = 0;
  __syncthreads();
  for (int base = 0; base < NN; base += 1024) {
    int i = base + tid;
    int v = (i < NN) ? cnt[i] : 0;
    int incl = v;
#pragma unroll
    for (int off = 1; off < 64; off <<= 1) {
      int t = __shfl_up(incl, off);
      if (lane >= off) incl += t;
    }
    if (lane == 63) wsum[wid] = incl;
    __syncthreads();
    int woff = 0;
    for (int w = 0; w < wid; ++w) woff += wsum[w];
    int excl = carry_s + woff + (incl - v);
    if (i < NN) row_start[i] = excl;
    __syncthreads();
    if (tid == 1023) carry_s = excl + v;
    __syncthreads();
  }
  if (threadIdx.x == 0) row_start[NN] = carry_s;
}

__global__ __launch_bounds__(256) void k_fill(const int* __restrict__ src, const int* __restrict__ dst,
    const int* __restrict__ row_start, int* __restrict__ fill,
    const float* __restrict__ dinv, int* __restrict__ csr_src, float* __restrict__ csr_coef) {
  int e = blockIdx.x * 256 + threadIdx.x;
  if (e >= NE) return;
  int s = src[e], d = dst[e];
  if ((unsigned)s >= (unsigned)NN || (unsigned)d >= (unsigned)NN) return;
  int pos = row_start[d] + atomicAdd(&fill[d], 1);
  csr_src[pos] = s;
  csr_coef[pos] = dinv[s] * dinv[d];
}

// ---------------- conversion kernels ----------------

// x [N,256] fp32 -> hi/lo fp16 (no relu, no transpose)
__global__ __launch_bounds__(256) void k_cvt_x(const float* __restrict__ x,
    _Float16* __restrict__ xhi, _Float16* __restrict__ xlo, int n4) {
  int i = blockIdx.x * 256 + threadIdx.x;
  if (i >= n4) return;
  f4 v = ((const f4*)x)[i];
  half4 h, l;
#pragma unroll
  for (int c = 0; c < 4; ++c) {
    float vv = v[c];
    _Float16 hh = (_Float16)vv;
    h[c] = hh;
    l[c] = (_Float16)(vv - (float)hh);
  }
  ((half4*)xhi)[i] = h;
  ((half4*)xlo)[i] = l;
}

// W [K,N] fp32 -> transposed hi/lo fp16 [N,K]  (z = matrix index)
__global__ __launch_bounds__(256) void k_cvt_wt(const float* __restrict__ W,
    _Float16* __restrict__ Whi, _Float16* __restrict__ Wlo, int K, int N) {
  __shared__ float tile[32][33];
  int l = blockIdx.z;
  const float* Wl = W + (size_t)l * K * N;
  _Float16* Oh = Whi + (size_t)l * K * N;
  _Float16* Ol = Wlo + (size_t)l * K * N;
  int k0 = blockIdx.x * 32, n0 = blockIdx.y * 32;
  int tx = threadIdx.x & 31, ty = threadIdx.x >> 5;
#pragma unroll
  for (int p = 0; p < 4; ++p)
    tile[ty + 8 * p][tx] = Wl[(size_t)(k0 + ty + 8 * p) * N + n0 + tx];
  __syncthreads();
#pragma unroll
  for (int p = 0; p < 4; ++p) {
    int n = n0 + ty + 8 * p, k = k0 + tx;
    float v = tile[tx][ty + 8 * p];
    _Float16 hi = (_Float16)v;
    Oh[(size_t)n * K + k] = hi;
    Ol[(size_t)n * K + k] = (_Float16)(v - (float)hi);
  }
}

// ---------------- MFMA GEMM: C[M,512] = (Ahi+Alo)[M,K] @ (Bhi+Blo)^T ----------------
// A: [M,K] fp16 hi/lo; B: [N,K] fp16 hi/lo (pre-transposed, k-contiguous)
// fp32-accurate via 3-term split: ah*bh + ah*bl + al*bh
// XCD swizzle: blocks round-robin to XCDs by id%8 (heuristic); map so the 4
// column-tiles of one A row-block are CONSECUTIVE SLOTS on ONE XCD -> A-tile
// fetched ~once into that XCD's L2 (was 4 XCDs x 1 fetch = 4x EA traffic).

#define LDK 40  // 32 + 8 pad: b128 frag reads land 2-way/bank (free)

__global__ __launch_bounds__(256) void k_gemm16(
    const _Float16* __restrict__ Ahi, const _Float16* __restrict__ Alo,
    const _Float16* __restrict__ Bhi, const _Float16* __restrict__ Blo,
    float* __restrict__ C, int M, int K) {
  const int nrb = (M + 127) >> 7;         // row blocks (391)
  const int rpx = (nrb + 7) >> 3;         // row blocks per XCD (49)
  const int f = blockIdx.x;
  const int q = f & 7, s = f >> 3;
  const int rb = q * rpx + (s >> 2);
  const int cb = s & 3;
  if (rb >= nrb) return;
  const int row0 = rb * 128, col0 = cb * 128;

  __shared__ _Float16 As[2][128][LDK];
  __shared__ _Float16 Bs[2][128][LDK];
  const int tid = threadIdx.x;
  const int lane = tid & 63, wave = tid >> 6;
  const int wm = wave & 1, wn = wave >> 1;
  const int quad = lane >> 4, r = lane & 15;

  f32x4 acc[4][4];
#pragma unroll
  for (int i = 0; i < 4; ++i)
#pragma unroll
    for (int j = 0; j < 4; ++j) acc[i][j] = (f32x4){0.f, 0.f, 0.f, 0.f};

  for (int k0 = 0; k0 < K; k0 += 32) {
    // stage A & B tiles (hi + lo) : 128 rows x 32 k each
#pragma unroll
    for (int j = 0; j < 2; ++j) {
      int c = tid + j * 256;
      int rrow = c >> 2, kc = (c & 3) * 8;
      int grow = row0 + rrow;
      half8 vh = {}, vl = {};
      if (grow < M) {
        vh = *(const half8*)(Ahi + (size_t)grow * K + k0 + kc);
        vl = *(const half8*)(Alo + (size_t)grow * K + k0 + kc);
      }
      *(half8*)&As[0][rrow][kc] = vh;
      *(half8*)&As[1][rrow][kc] = vl;
      int gn = col0 + rrow;
      *(half8*)&Bs[0][rrow][kc] = *(const half8*)(Bhi + (size_t)gn * K + k0 + kc);
      *(half8*)&Bs[1][rrow][kc] = *(const half8*)(Blo + (size_t)gn * K + k0 + kc);
    }
    __syncthreads();

    half8 ah[4], al[4], bh[4], bl[4];
#pragma unroll
    for (int mi = 0; mi < 4; ++mi) {
      int mrow = wm * 64 + mi * 16 + r;
      ah[mi] = *(const half8*)&As[0][mrow][quad * 8];
      al[mi] = *(const half8*)&As[1][mrow][quad * 8];
    }
#pragma unroll
    for (int ni = 0; ni < 4; ++ni) {
      int nrow = wn * 64 + ni * 16 + r;
      bh[ni] = *(const half8*)&Bs[0][nrow][quad * 8];
      bl[ni] = *(const half8*)&Bs[1][nrow][quad * 8];
    }
#pragma unroll
    for (int mi = 0; mi < 4; ++mi)
#pragma unroll
      for (int ni = 0; ni < 4; ++ni) {
        acc[mi][ni] = __builtin_amdgcn_mfma_f32_16x16x32_f16(ah[mi], bh[ni], acc[mi][ni], 0, 0, 0);
        acc[mi][ni] = __builtin_amdgcn_mfma_f32_16x16x32_f16(ah[mi], bl[ni], acc[mi][ni], 0, 0, 0);
        acc[mi][ni] = __builtin_amdgcn_mfma_f32_16x16x32_f16(al[mi], bh[ni], acc[mi][ni], 0, 0, 0);
      }
    __syncthreads();
  }

  // epilogue: C/D layout col=lane&15, row=quad*4+reg. Nontemporal: Y is consumed
  // by the (random-XCD) gather next -- writer-L2 residency is mostly wasted.
#pragma unroll
  for (int mi = 0; mi < 4; ++mi)
#pragma unroll
    for (int reg = 0; reg < 4; ++reg) {
      int grow = row0 + wm * 64 + mi * 16 + quad * 4 + reg;
      if (grow < M) {
#pragma unroll
        for (int ni = 0; ni < 4; ++ni)
          nt_store(&C[(size_t)grow * HDIM + col0 + wn * 64 + ni * 16 + r], acc[mi][ni][reg]);
      }
    }
}

// ---------------- CSR aggregation (panel split; unroll-4 for MLP) ----------------
// xrelu = relu(b + dinv_i^2*h_i + sum coef*h_src); emit fp16 hi/lo (+ optional fp32)

__global__ __launch_bounds__(256) void k_agg(const float* __restrict__ h,
    _Float16* __restrict__ xhi, _Float16* __restrict__ xlo, float* __restrict__ xf,
    const int* __restrict__ row_start, const int* __restrict__ csr_src,
    const float* __restrict__ csr_coef, const float* __restrict__ dinv,
    const float* __restrict__ bias) {
  int wid = threadIdx.x >> 6, lane = threadIdx.x & 63;
  int i = blockIdx.x * 4 + wid;
  if (i >= NN) return;
  int c = blockIdx.y * 256 + lane * 4;
  float di = dinv[i];
  float d2 = di * di;
  f4 a0 = *(const f4*)(h + (size_t)i * HDIM + c) * d2;
  f4 a1 = {0.f, 0.f, 0.f, 0.f}, a2 = a1, a3 = a1;
  int e0 = row_start[i], e1 = row_start[i + 1];
  int e = e0;
  // 4 independent gathers in flight per wave (MLP)
  for (; e + 4 <= e1; e += 4) {
    int s0 = csr_src[e], s1 = csr_src[e + 1], s2 = csr_src[e + 2], s3 = csr_src[e + 3];
    float c0 = csr_coef[e], c1 = csr_coef[e + 1], c2 = csr_coef[e + 2], c3 = csr_coef[e + 3];
    f4 r0 = *(const f4*)(h + (size_t)s0 * HDIM + c);
    f4 r1 = *(const f4*)(h + (size_t)s1 * HDIM + c);
    f4 r2 = *(const f4*)(h + (size_t)s2 * HDIM + c);
    f4 r3 = *(const f4*)(h + (size_t)s3 * HDIM + c);
    a0 += r0 * c0; a1 += r1 * c1; a2 += r2 * c2; a3 += r3 * c3;
  }
  for (; e < e1; ++e) {
    int s = csr_src[e];
    float cf = csr_coef[e];
    a0 += *(const f4*)(h + (size_t)s * HDIM + c) * cf;
  }
  f4 acc = (a0 + a1) + (a2 + a3);
  acc += *(const f4*)(bias + c);
#pragma unroll
  for (int q = 0; q < 4; ++q) acc[q] = fmaxf(acc[q], 0.f);
  half4 hh, ll;
#pragma unroll
  for (int q = 0; q < 4; ++q) {
    _Float16 hv = (_Float16)acc[q];
    hh[q] = hv;
    ll[q] = (_Float16)(acc[q] - (float)hv);
  }
  nt_store((half4*)(xhi + (size_t)i * HDIM + c), hh);
  nt_store((half4*)(xlo + (size_t)i * HDIM + c), ll);
  if (xf) nt_store((f4*)(xf + (size_t)i * HDIM + c), acc);
}

// final conv: h3[N,3] = X[N,512] @ W1[512,3]; one wave per node
__global__ __launch_bounds__(256) void k_gemm3(const float* __restrict__ X, const float* __restrict__ W1,
    float* __restrict__ h3) {
  int wid = threadIdx.x >> 6, lane = threadIdx.x & 63;
  int i = blockIdx.x * 4 + wid;
  if (i >= NN) return;
  const float* xi = X + (size_t)i * HDIM;
  float a0 = 0.f, a1 = 0.f, a2 = 0.f;
#pragma unroll
  for (int t = 0; t < HDIM / 64; ++t) {
    int k = t * 64 + lane;
    float v = xi[k];
    a0 = fmaf(v, W1[k * 3 + 0], a0);
    a1 = fmaf(v, W1[k * 3 + 1], a1);
    a2 = fmaf(v, W1[k * 3 + 2], a2);
  }
#pragma unroll
  for (int off = 32; off > 0; off >>= 1) {
    a0 += __shfl_down(a0, off);
    a1 += __shfl_down(a1, off);
    a2 += __shfl_down(a2, off);
  }
  if (lane == 0) {
    h3[(size_t)i * 3 + 0] = a0;
    h3[(size_t)i * 3 + 1] = a1;
    h3[(size_t)i * 3 + 2] = a2;
  }
}

__global__ __launch_bounds__(256) void k_agg3(const float* __restrict__ h3, float* __restrict__ out,
    const int* __restrict__ row_start, const int* __restrict__ csr_src,
    const float* __restrict__ csr_coef, const float* __restrict__ dinv,
    const float* __restrict__ b1) {
  int i = blockIdx.x * 256 + threadIdx.x;
  if (i >= NN) return;
  float d2 = dinv[i] * dinv[i];
  float o0 = h3[(size_t)i * 3 + 0] * d2;
  float o1 = h3[(size_t)i * 3 + 1] * d2;
  float o2 = h3[(size_t)i * 3 + 2] * d2;
  int e0 = row_start[i], e1 = row_start[i + 1];
  for (int e = e0; e < e1; ++e) {
    int s = csr_src[e];
    float c = csr_coef[e];
    o0 = fmaf(c, h3[(size_t)s * 3 + 0], o0);
    o1 = fmaf(c, h3[(size_t)s * 3 + 1], o1);
    o2 = fmaf(c, h3[(size_t)s * 3 + 2], o2);
  }
  out[(size_t)i * 3 + 0] = o0 + b1[0];
  out[(size_t)i * 3 + 1] = o1 + b1[1];
  out[(size_t)i * 3 + 2] = o2 + b1[2];
}

// ---------------- launch ----------------

extern "C" void kernel_launch(void* const* d_in, const int* in_sizes, int n_in,
                              void* d_out, int out_size, void* d_ws, size_t ws_size,
                              hipStream_t stream) {
  const float* x  = (const float*)d_in[0];
  const int*   ei = (const int*)d_in[1];
  const float* W0 = (const float*)d_in[2];
  const float* b0 = (const float*)d_in[3];
  const float* Wr = (const float*)d_in[4];
  const float* br = (const float*)d_in[5];
  const float* W1 = (const float*)d_in[6];
  const float* b1 = (const float*)d_in[7];
  float* out = (float*)d_out;
  float* X = out + (size_t)NN * CDIM;  // final relu'd state [NN, HDIM] == output 1

  char* ws = (char*)d_ws;
  size_t off = 0;
  auto alloc = [&](size_t bytes) -> void* {
    void* p = ws + off;
    off = (off + bytes + 255) & ~(size_t)255;
    return p;
  };
  float*     Y      = (float*)alloc((size_t)NN * HDIM * 4);        // 102.4 MB
  _Float16*  Xhi    = (_Float16*)alloc((size_t)NN * HDIM * 2);     // 51.2 MB
  _Float16*  Xlo    = (_Float16*)alloc((size_t)NN * HDIM * 2);     // 51.2 MB
  _Float16*  W0thi  = (_Float16*)alloc((size_t)FDIM * HDIM * 2);
  _Float16*  W0tlo  = (_Float16*)alloc((size_t)FDIM * HDIM * 2);
  _Float16*  Wrthi  = (_Float16*)alloc((size_t)NBLK * 2 * HDIM * HDIM * 2);
  _Float16*  Wrtlo  = (_Float16*)alloc((size_t)NBLK * 2 * HDIM * HDIM * 2);
  float*     csr_coef = (float*)alloc((size_t)NE * 4);
  float*     dinv     = (float*)alloc((size_t)NN * 4);
  float*     h3       = (float*)alloc((size_t)NN * CDIM * 4);
  int*       cnt      = (int*)alloc((size_t)NN * 4);
  int*       fill     = (int*)alloc((size_t)NN * 4);
  int*       row_start= (int*)alloc((size_t)(NN + 1) * 4);
  int*       csr_src  = (int*)alloc((size_t)NE * 4);

  const int* src = ei;
  const int* dst = ei + NE;

  // ---- setup (once per call; reused by all 14 layers) ----
  k_zero_i32<<<(NN + 255) / 256, 256, 0, stream>>>(cnt, NN);
  k_zero_i32<<<(NN + 255) / 256, 256, 0, stream>>>(fill, NN);
  k_hist<<<(NE + 255) / 256, 256, 0, stream>>>(dst, cnt);
  k_dinv<<<(NN + 255) / 256, 256, 0, stream>>>(cnt, dinv);
  k_scan<<<1, 1024, 0, stream>>>(cnt, row_start);
  k_fill<<<(NE + 255) / 256, 256, 0, stream>>>(src, dst, row_start, fill, dinv, csr_src, csr_coef);

  // weight + input conversion (hi/lo fp16, weights transposed to [N][K])
  k_cvt_x<<<(NN * FDIM / 4 + 255) / 256, 256, 0, stream>>>(x, Xhi, Xlo, NN * FDIM / 4);
  {
    dim3 g0(FDIM / 32, HDIM / 32, 1);
    k_cvt_wt<<<g0, 256, 0, stream>>>(W0, W0thi, W0tlo, FDIM, HDIM);
    dim3 gr(HDIM / 32, HDIM / 32, NBLK * 2);
    k_cvt_wt<<<gr, 256, 0, stream>>>(Wr, Wrthi, Wrtlo, HDIM, HDIM);
  }

  const int nrb = (NN + 127) / 128;          // 391 row blocks
  const int rpx = (nrb + 7) / 8;             // 49 per XCD
  const int gemm_blocks = 8 * rpx * 4;       // 1568 (XCD-swizzled 1D grid)
  dim3 agg_grid((NN + 3) / 4, 2);            // y = feature panel (256 feats)

  // conv0: (x0 hi/lo live in the head of Xhi/Xlo; consumed before agg overwrites)
  k_gemm16<<<gemm_blocks, 256, 0, stream>>>(Xhi, Xlo, W0thi, W0tlo, Y, NN, FDIM);
  k_agg<<<agg_grid, 256, 0, stream>>>(Y, Xhi, Xlo, nullptr, row_start, csr_src, csr_coef, dinv, b0);

  // 6 residual blocks x 2 convs, all H->H
  for (int ib = 0; ib < NBLK; ++ib) {
    for (int j = 0; j < 2; ++j) {
      int li = ib * 2 + j;
      const _Float16* Wh = Wrthi + (size_t)li * HDIM * HDIM;
      const _Float16* Wl = Wrtlo + (size_t)li * HDIM * HDIM;
      const float* bb = br + (size_t)li * HDIM;
      bool last = (ib == NBLK - 1) && (j == 1);
      k_gemm16<<<gemm_blocks, 256, 0, stream>>>(Xhi, Xlo, Wh, Wl, Y, NN, HDIM);
      k_agg<<<agg_grid, 256, 0, stream>>>(Y, Xhi, Xlo, last ? X : nullptr,
                                          row_start, csr_src, csr_coef, dinv, bb);
    }
  }

  // final conv: X (relu'd, fp32) @ W1 -> out[N,3]
  k_gemm3<<<(NN + 3) / 4, 256, 0, stream>>>(X, W1, h3);
  k_agg3<<<(NN + 255) / 256, 256, 0, stream>>>(h3, out, row_start, csr_src, csr_coef, dinv, b1);
}